// Round 1
// baseline (1254.290 us; speedup 1.0000x reference)
//
#include <hip/hip_runtime.h>
#include <hip/hip_bf16.h>
#include <math.h>

#define DIMK 1024
#define NH 16
#define HD 64
#define BB 4
#define SS 8192

#define TM 128
#define TN 128
#define TK 16

// ---------------- fill d_out with bo broadcast ----------------
__global__ __launch_bounds__(256) void fill_out_kernel(const float4* __restrict__ bo4,
                                                       float4* __restrict__ out, int total4) {
  for (int i = blockIdx.x * 256 + threadIdx.x; i < total4; i += gridDim.x * 256)
    out[i] = bo4[i & 255];  // DIMK/4 == 256
}

// ---------------- gathered projection GEMM: out[m,:] = x[b, idx[e], :] @ W + bias ----------------
__global__ __launch_bounds__(256) void proj_gemm(
    const float* __restrict__ X, const int* __restrict__ idx,
    const float* __restrict__ W, const float* __restrict__ bias,
    float* __restrict__ out, int M, int E) {
  __shared__ float As[TK][TM];      // [k][m]
  __shared__ float Bs[TK][TN + 4];  // [k][n] pad
  const int tid = threadIdx.x;
  const int m0 = blockIdx.x * TM, n0 = blockIdx.y * TN;
  const int tx = tid & 15, ty = tid >> 4;

  float acc[8][8];
#pragma unroll
  for (int i = 0; i < 8; i++)
#pragma unroll
    for (int j = 0; j < 8; j++) acc[i][j] = 0.f;

  // per-thread A-load row pointers (2 float4 loads per k-tile)
  const float* rp[2];
  bool ok[2];
#pragma unroll
  for (int i = 0; i < 2; i++) {
    int l = i * 256 + tid;
    int m = l >> 2, c4 = l & 3;
    int mg = m0 + m;
    ok[i] = (mg < M);
    if (ok[i]) {
      int b = mg / E;
      int e = mg - b * E;
      rp[i] = X + ((size_t)(b * SS + idx[e])) * DIMK + c4 * 4;
    } else {
      rp[i] = X;  // dummy, never read
    }
  }

  for (int k0 = 0; k0 < DIMK; k0 += TK) {
#pragma unroll
    for (int i = 0; i < 2; i++) {
      int l = i * 256 + tid;
      int m = l >> 2, c4 = l & 3;
      float4 v = make_float4(0.f, 0.f, 0.f, 0.f);
      if (ok[i]) v = *(const float4*)(rp[i] + k0);
      As[c4 * 4 + 0][m] = v.x;
      As[c4 * 4 + 1][m] = v.y;
      As[c4 * 4 + 2][m] = v.z;
      As[c4 * 4 + 3][m] = v.w;
    }
#pragma unroll
    for (int i = 0; i < 2; i++) {
      int l = i * 256 + tid;
      int k = l >> 5, c4 = l & 31;
      *(float4*)&Bs[k][c4 * 4] = *(const float4*)(W + (size_t)(k0 + k) * DIMK + n0 + c4 * 4);
    }
    __syncthreads();
#pragma unroll
    for (int k = 0; k < TK; k++) {
      float a[8], b[8];
      *(float4*)&a[0] = *(float4*)&As[k][ty * 8];
      *(float4*)&a[4] = *(float4*)&As[k][ty * 8 + 4];
      *(float4*)&b[0] = *(float4*)&Bs[k][tx * 8];
      *(float4*)&b[4] = *(float4*)&Bs[k][tx * 8 + 4];
#pragma unroll
      for (int i = 0; i < 8; i++)
#pragma unroll
        for (int j = 0; j < 8; j++) acc[i][j] = fmaf(a[i], b[j], acc[i][j]);
    }
    __syncthreads();
  }

  float4 bs0 = *(const float4*)(bias + n0 + tx * 8);
  float4 bs1 = *(const float4*)(bias + n0 + tx * 8 + 4);
#pragma unroll
  for (int i = 0; i < 8; i++) {
    int mg = m0 + ty * 8 + i;
    if (mg >= M) continue;
    float* orow = out + (size_t)mg * DIMK + n0 + tx * 8;
    float4 r0, r1;
    r0.x = acc[i][0] + bs0.x; r0.y = acc[i][1] + bs0.y;
    r0.z = acc[i][2] + bs0.z; r0.w = acc[i][3] + bs0.w;
    r1.x = acc[i][4] + bs1.x; r1.y = acc[i][5] + bs1.y;
    r1.z = acc[i][6] + bs1.z; r1.w = acc[i][7] + bs1.w;
    *(float4*)orow = r0;
    *(float4*)(orow + 4) = r1;
  }
}

// ---------------- edge MLP scores: one wave per (b,h,e) ----------------
__global__ __launch_bounds__(256) void edge_scores(
    const float* __restrict__ qs, const float* __restrict__ kd,
    const float* __restrict__ W1, const float* __restrict__ b1,
    const float* __restrict__ W2, const float* __restrict__ b2,
    float* __restrict__ scores, int E) {
  __shared__ float efs[4][128];
  const int w = threadIdx.x >> 6, lane = threadIdx.x & 63;
  const int eh = blockIdx.x * 4 + w;  // < B*H*E (grid exact)
  const int HE = NH * E;
  const int b = eh / HE;
  const int r = eh - b * HE;
  const int h = r / E;
  const int e = r - h * E;
  const size_t base = ((size_t)(b * E + e)) * DIMK + h * HD;
  efs[w][lane] = qs[base + lane];
  efs[w][64 + lane] = kd[base + lane];
  __syncthreads();
  float dot = 0.f;
#pragma unroll 16
  for (int i = 0; i < 128; i++) dot = fmaf(efs[w][i], W1[i * HD + lane], dot);
  float hv = dot + b1[lane];
  hv = 0.5f * hv * (1.f + erff(hv * 0.70710678118654752f));  // exact GELU
  float p = hv * W2[lane];
#pragma unroll
  for (int off = 32; off; off >>= 1) p += __shfl_xor(p, off, 64);
  if (lane == 0) scores[(size_t)(b * NH + h) * E + e] = (p + b2[0]) * 0.125f;  // hd^-0.5
}

// ---------------- softmax over E per (b,h), then *= edge_weight[h] ----------------
__global__ __launch_bounds__(256) void softmax_ew(float* __restrict__ scores,
                                                  const float* __restrict__ ew, int E) {
  const int row = blockIdx.x;  // b*NH + h
  const int h = row & (NH - 1);
  float* s = scores + (size_t)row * E;
  const int tid = threadIdx.x, lane = tid & 63, w = tid >> 6;
  __shared__ float red[4];

  float vals[8];
  float mx = -1e30f;
#pragma unroll
  for (int i = 0; i < 8; i++) {
    int j = tid + i * 256;
    vals[i] = (j < E) ? s[j] : -1e30f;
    mx = fmaxf(mx, vals[i]);
  }
#pragma unroll
  for (int off = 32; off; off >>= 1) mx = fmaxf(mx, __shfl_xor(mx, off, 64));
  if (lane == 0) red[w] = mx;
  __syncthreads();
  mx = fmaxf(fmaxf(red[0], red[1]), fmaxf(red[2], red[3]));
  __syncthreads();

  float sum = 0.f;
#pragma unroll
  for (int i = 0; i < 8; i++) {
    vals[i] = __expf(vals[i] - mx);
    if (tid + i * 256 < E) sum += vals[i];
  }
#pragma unroll
  for (int off = 32; off; off >>= 1) sum += __shfl_xor(sum, off, 64);
  if (lane == 0) red[w] = sum;
  __syncthreads();
  sum = red[0] + red[1] + red[2] + red[3];

  const float scaleout = ew[h] / sum;
#pragma unroll
  for (int i = 0; i < 8; i++) {
    int j = tid + i * 256;
    if (j < E) s[j] = vals[i] * scaleout;
  }
}

// ---------------- final GEMM: (attn*v_dst)[m,:] @ Wo, atomic row-scatter by src ----------------
__global__ __launch_bounds__(256) void final_gemm(
    const float* __restrict__ V, const float* __restrict__ attn,
    const float* __restrict__ Wo, const int* __restrict__ srci,
    float* __restrict__ out, int M, int E) {
  __shared__ float As[TK][TM];
  __shared__ float Bs[TK][TN + 4];
  const int tid = threadIdx.x;
  const int m0 = blockIdx.x * TM, n0 = blockIdx.y * TN;
  const int tx = tid & 15, ty = tid >> 4;

  float acc[8][8];
#pragma unroll
  for (int i = 0; i < 8; i++)
#pragma unroll
    for (int j = 0; j < 8; j++) acc[i][j] = 0.f;

  const float* rp[2];
  const float* ar[2];
  bool ok[2];
#pragma unroll
  for (int i = 0; i < 2; i++) {
    int l = i * 256 + tid;
    int m = l >> 2, c4 = l & 3;
    int mg = m0 + m;
    ok[i] = (mg < M);
    if (ok[i]) {
      int b = mg / E;
      int e = mg - b * E;
      rp[i] = V + (size_t)mg * DIMK + c4 * 4;
      ar[i] = attn + (size_t)(b * NH) * E + e;
    } else {
      rp[i] = V;
      ar[i] = attn;
    }
  }

  for (int k0 = 0; k0 < DIMK; k0 += TK) {
    const int h = k0 >> 6;  // c4*4 <= 12 and k0 % 64 in {0,16,32,48} -> same head for whole float4
#pragma unroll
    for (int i = 0; i < 2; i++) {
      int l = i * 256 + tid;
      int m = l >> 2, c4 = l & 3;
      float4 v = make_float4(0.f, 0.f, 0.f, 0.f);
      if (ok[i]) {
        v = *(const float4*)(rp[i] + k0);
        float av = ar[i][(size_t)h * E];
        v.x *= av; v.y *= av; v.z *= av; v.w *= av;
      }
      As[c4 * 4 + 0][m] = v.x;
      As[c4 * 4 + 1][m] = v.y;
      As[c4 * 4 + 2][m] = v.z;
      As[c4 * 4 + 3][m] = v.w;
    }
#pragma unroll
    for (int i = 0; i < 2; i++) {
      int l = i * 256 + tid;
      int k = l >> 5, c4 = l & 31;
      *(float4*)&Bs[k][c4 * 4] = *(const float4*)(Wo + (size_t)(k0 + k) * DIMK + n0 + c4 * 4);
    }
    __syncthreads();
#pragma unroll
    for (int k = 0; k < TK; k++) {
      float a[8], b[8];
      *(float4*)&a[0] = *(float4*)&As[k][ty * 8];
      *(float4*)&a[4] = *(float4*)&As[k][ty * 8 + 4];
      *(float4*)&b[0] = *(float4*)&Bs[k][tx * 8];
      *(float4*)&b[4] = *(float4*)&Bs[k][tx * 8 + 4];
#pragma unroll
      for (int i = 0; i < 8; i++)
#pragma unroll
        for (int j = 0; j < 8; j++) acc[i][j] = fmaf(a[i], b[j], acc[i][j]);
    }
    __syncthreads();
  }

#pragma unroll
  for (int i = 0; i < 8; i++) {
    int mg = m0 + ty * 8 + i;
    if (mg >= M) continue;
    int b = mg / E;
    int e = mg - b * E;
    int srow = srci[e];
    float* orow = out + ((size_t)b * SS + srow) * DIMK + n0 + tx * 8;
#pragma unroll
    for (int j = 0; j < 8; j++) atomicAdd(&orow[j], acc[i][j]);
  }
}

extern "C" void kernel_launch(void* const* d_in, const int* in_sizes, int n_in,
                              void* d_out, int out_size, void* d_ws, size_t ws_size,
                              hipStream_t stream) {
  const float* x = (const float*)d_in[0];
  const int* src = (const int*)d_in[1];
  const int* dst = (const int*)d_in[2];
  const float* Wq = (const float*)d_in[3];
  const float* bq = (const float*)d_in[4];
  const float* Wk = (const float*)d_in[5];
  const float* bk = (const float*)d_in[6];
  const float* Wv = (const float*)d_in[7];
  const float* bv = (const float*)d_in[8];
  const float* Wo = (const float*)d_in[9];
  const float* bo = (const float*)d_in[10];
  const float* ew = (const float*)d_in[11];
  const float* W1 = (const float*)d_in[12];
  const float* b1 = (const float*)d_in[13];
  const float* W2 = (const float*)d_in[14];
  const float* b2 = (const float*)d_in[15];
  float* out = (float*)d_out;

  const int E = in_sizes[1];
  const int M = BB * E;

  float* qs = (float*)d_ws;                   // M*DIMK
  float* kd = qs + (size_t)M * DIMK;          // M*DIMK
  float* sc = kd + (size_t)M * DIMK;          // BB*NH*E
  float* vd = qs;                             // reuse qs after scores computed

  // 1) fill output with bo (rows not touched by src keep exactly bo)
  const int total4 = BB * SS * (DIMK / 4);
  fill_out_kernel<<<2048, 256, 0, stream>>>((const float4*)bo, (float4*)out, total4);

  dim3 g1((M + TM - 1) / TM, DIMK / TN);
  // 2) gathered projections (only rows that are ever used)
  proj_gemm<<<g1, 256, 0, stream>>>(x, src, Wq, bq, qs, M, E);
  proj_gemm<<<g1, 256, 0, stream>>>(x, dst, Wk, bk, kd, M, E);

  // 3) edge MLP -> scores
  edge_scores<<<(BB * NH * E) / 4, 256, 0, stream>>>(qs, kd, W1, b1, W2, b2, sc, E);

  // 4) softmax over edges + edge_weight
  softmax_ew<<<BB * NH, 256, 0, stream>>>(sc, ew, E);

  // 5) v projection (reuses qs buffer)
  proj_gemm<<<g1, 256, 0, stream>>>(x, dst, Wv, bv, vd, M, E);

  // 6) weighted V @ Wo with atomic scatter into out rows src[e]
  final_gemm<<<g1, 256, 0, stream>>>(vd, sc, Wo, src, out, M, E);
}

// Round 2
// 644.771 us; speedup vs baseline: 1.9453x; 1.9453x over previous
//
#include <hip/hip_runtime.h>
#include <hip/hip_bf16.h>
#include <math.h>

#define DIMK 1024
#define NH 16
#define HD 64
#define BB 4
#define SS 8192

typedef __attribute__((ext_vector_type(8))) short bf16x8;
typedef __attribute__((ext_vector_type(8))) unsigned short ushort8;
typedef __attribute__((ext_vector_type(4))) float f32x4;

#define MFMA16(a, b, c) __builtin_amdgcn_mfma_f32_16x16x32_bf16((a), (b), (c), 0, 0, 0)

__device__ __forceinline__ unsigned short f32_to_bf16_rne(float f) {
  unsigned int u = __float_as_uint(f);
  u = (u + 0x7fffu + ((u >> 16) & 1u)) >> 16;
  return (unsigned short)u;
}
__device__ __forceinline__ float bf16_bits_to_f32(unsigned short b) {
  return __uint_as_float(((unsigned int)b) << 16);
}

// ---------------- fill d_out with bo broadcast ----------------
__global__ __launch_bounds__(256) void fill_out_kernel(const float4* __restrict__ bo4,
                                                       float4* __restrict__ out, int total4) {
  for (int i = blockIdx.x * 256 + threadIdx.x; i < total4; i += gridDim.x * 256)
    out[i] = bo4[i & 255];  // DIMK/4 == 256
}

// ---------------- split W [k][n] fp32 -> WT_hi/WT_lo [n][k] bf16 ----------------
__global__ __launch_bounds__(256) void prep_w(const float* __restrict__ W,
                                              unsigned short* __restrict__ WT_hi,
                                              unsigned short* __restrict__ WT_lo) {
  __shared__ float st[64][65];
  const int bk = blockIdx.x * 64, bn = blockIdx.y * 64;
  const int t = threadIdx.x;
  const int lr = t >> 4, lc = (t & 15) * 4;
#pragma unroll
  for (int i = 0; i < 4; i++) {
    int k = lr + i * 16;
    float4 v = *(const float4*)(W + (size_t)(bk + k) * DIMK + bn + lc);
    st[k][lc] = v.x; st[k][lc + 1] = v.y; st[k][lc + 2] = v.z; st[k][lc + 3] = v.w;
  }
  __syncthreads();
#pragma unroll
  for (int i = 0; i < 4; i++) {
    int n = lr + i * 16;
    unsigned long long ph = 0, pl = 0;
#pragma unroll
    for (int j = 0; j < 4; j++) {
      float v = st[lc + j][n];
      unsigned short hb = f32_to_bf16_rne(v);
      unsigned short lb = f32_to_bf16_rne(v - bf16_bits_to_f32(hb));
      ph |= ((unsigned long long)hb) << (16 * j);
      pl |= ((unsigned long long)lb) << (16 * j);
    }
    *(unsigned long long*)(WT_hi + (size_t)(bn + n) * DIMK + bk + lc) = ph;
    *(unsigned long long*)(WT_lo + (size_t)(bn + n) * DIMK + bk + lc) = pl;
  }
}

// ---------------- first-occurrence map f[e] = min{e' : src[e']==src[e]} ----------------
__global__ __launch_bounds__(256) void calc_first(const int* __restrict__ src,
                                                  int* __restrict__ f, int E) {
  __shared__ int s[2048];
  for (int i = threadIdx.x; i < E; i += 256) s[i] = src[i];
  __syncthreads();
  int e = blockIdx.x * 256 + threadIdx.x;
  if (e >= E) return;
  int se = s[e], r = e;
  for (int j = 0; j < e; j++)
    if (s[j] == se) { r = j; break; }
  f[e] = r;
}

// ---------------- split-bf16 MFMA GEMM ----------------
// MODE 0: A row m -> x[b*SS + gidx[e]], store out[m][n] = acc + bias[n]
// MODE 1: A row m -> X[m] (wrow), store out[b*SS+srci[e]][n] = acc + bias[n] iff fidx[e]==e
template <int MODE>
__global__ __launch_bounds__(256) void gemm_split(
    const float* __restrict__ X, const int* __restrict__ gidx,
    const unsigned short* __restrict__ BT_hi, const unsigned short* __restrict__ BT_lo,
    const float* __restrict__ bias, float* __restrict__ out,
    const int* __restrict__ fidx, const int* __restrict__ srci, int M, int E) {
  __shared__ unsigned short As_hi[128][40];
  __shared__ unsigned short As_lo[128][40];
  __shared__ unsigned short Bs_hi[128][40];
  __shared__ unsigned short Bs_lo[128][40];

  const int tid = threadIdx.x;
  const int m0 = blockIdx.x * 128, n0 = blockIdx.y * 128;
  const int lane = tid & 63, w = tid >> 6;
  const int wm0 = (w >> 1) * 64, wn0 = (w & 1) * 64;

  // staging roles: thread stages A row sm (k-range skq..skq+15) and B row sm
  const int sm = tid >> 1;
  const int skq = (tid & 1) * 16;

  const int mg = m0 + sm;
  const float* arow;
  if (MODE == 0) {
    int mgc = (mg < M) ? mg : 0;
    int b = mgc / E, e = mgc - b * E;
    arow = X + ((size_t)b * SS + gidx[e]) * DIMK;
  } else {
    arow = X + (size_t)((mg < M) ? mg : 0) * DIMK;
  }
  const unsigned short* bhrow = BT_hi + (size_t)(n0 + sm) * DIMK;
  const unsigned short* blrow = BT_lo + (size_t)(n0 + sm) * DIMK;

  f32x4 acc[4][4];
#pragma unroll
  for (int i = 0; i < 4; i++)
#pragma unroll
    for (int j = 0; j < 4; j++) acc[i][j] = (f32x4){0.f, 0.f, 0.f, 0.f};

  for (int k0 = 0; k0 < DIMK; k0 += 32) {
    // global loads (A fp32, B pre-split bf16)
    float4 a0 = *(const float4*)(arow + k0 + skq);
    float4 a1 = *(const float4*)(arow + k0 + skq + 4);
    float4 a2 = *(const float4*)(arow + k0 + skq + 8);
    float4 a3 = *(const float4*)(arow + k0 + skq + 12);
    ushort8 gbh0 = *(const ushort8*)(bhrow + k0 + skq);
    ushort8 gbh1 = *(const ushort8*)(bhrow + k0 + skq + 8);
    ushort8 gbl0 = *(const ushort8*)(blrow + k0 + skq);
    ushort8 gbl1 = *(const ushort8*)(blrow + k0 + skq + 8);

    // split A to hi/lo bf16
    float av[16];
    *(float4*)&av[0] = a0; *(float4*)&av[4] = a1;
    *(float4*)&av[8] = a2; *(float4*)&av[12] = a3;
    ushort8 h0, h1, l0, l1;
#pragma unroll
    for (int i = 0; i < 8; i++) {
      unsigned short hb = f32_to_bf16_rne(av[i]);
      h0[i] = hb;
      l0[i] = f32_to_bf16_rne(av[i] - bf16_bits_to_f32(hb));
    }
#pragma unroll
    for (int i = 0; i < 8; i++) {
      unsigned short hb = f32_to_bf16_rne(av[8 + i]);
      h1[i] = hb;
      l1[i] = f32_to_bf16_rne(av[8 + i] - bf16_bits_to_f32(hb));
    }

    __syncthreads();  // previous iter's LDS reads done
    *(ushort8*)&As_hi[sm][skq] = h0;
    *(ushort8*)&As_hi[sm][skq + 8] = h1;
    *(ushort8*)&As_lo[sm][skq] = l0;
    *(ushort8*)&As_lo[sm][skq + 8] = l1;
    *(ushort8*)&Bs_hi[sm][skq] = gbh0;
    *(ushort8*)&Bs_hi[sm][skq + 8] = gbh1;
    *(ushort8*)&Bs_lo[sm][skq] = gbl0;
    *(ushort8*)&Bs_lo[sm][skq + 8] = gbl1;
    __syncthreads();

    // fragment reads: A[row=l&15][k=(l>>4)*8+i], B[k][col=l&15] from BT rows
    bf16x8 fah[4], fal[4], fbh[4], fbl[4];
    const int kk = (lane >> 4) * 8;
    const int rr = lane & 15;
#pragma unroll
    for (int f = 0; f < 4; f++) {
      fah[f] = *(bf16x8*)&As_hi[wm0 + f * 16 + rr][kk];
      fal[f] = *(bf16x8*)&As_lo[wm0 + f * 16 + rr][kk];
      fbh[f] = *(bf16x8*)&Bs_hi[wn0 + f * 16 + rr][kk];
      fbl[f] = *(bf16x8*)&Bs_lo[wn0 + f * 16 + rr][kk];
    }
#pragma unroll
    for (int mf = 0; mf < 4; mf++)
#pragma unroll
      for (int nf = 0; nf < 4; nf++) {
        acc[mf][nf] = MFMA16(fah[mf], fbh[nf], acc[mf][nf]);
        acc[mf][nf] = MFMA16(fah[mf], fbl[nf], acc[mf][nf]);
        acc[mf][nf] = MFMA16(fal[mf], fbh[nf], acc[mf][nf]);
      }
  }

  // epilogue: C/D layout col=lane&15, row=(lane>>4)*4+r
  const int cq = lane >> 4, cr = lane & 15;
#pragma unroll
  for (int nf = 0; nf < 4; nf++) {
    const int col = n0 + wn0 + nf * 16 + cr;
    const float bv = bias[col];
#pragma unroll
    for (int mf = 0; mf < 4; mf++) {
#pragma unroll
      for (int r = 0; r < 4; r++) {
        const int mrow = m0 + wm0 + mf * 16 + cq * 4 + r;
        if (mrow >= M) continue;
        if (MODE == 0) {
          out[(size_t)mrow * DIMK + col] = acc[mf][nf][r] + bv;
        } else {
          int b = mrow / E, e = mrow - b * E;
          if (fidx[e] == e) {
            int orow = b * SS + srci[e];
            out[(size_t)orow * DIMK + col] = acc[mf][nf][r] + bv;
          }
        }
      }
    }
  }
}

// ---------------- edge MLP scores: one wave per (b,h,e) ----------------
__global__ __launch_bounds__(256) void edge_scores(
    const float* __restrict__ qs, const float* __restrict__ kd,
    const float* __restrict__ W1, const float* __restrict__ b1,
    const float* __restrict__ W2, const float* __restrict__ b2,
    float* __restrict__ scores, int E) {
  __shared__ float efs[4][128];
  const int w = threadIdx.x >> 6, lane = threadIdx.x & 63;
  const int eh = blockIdx.x * 4 + w;
  const int HE = NH * E;
  const int b = eh / HE;
  const int r = eh - b * HE;
  const int h = r / E;
  const int e = r - h * E;
  const size_t base = ((size_t)(b * E + e)) * DIMK + h * HD;
  efs[w][lane] = qs[base + lane];
  efs[w][64 + lane] = kd[base + lane];
  __syncthreads();
  float dot = 0.f;
#pragma unroll 16
  for (int i = 0; i < 128; i++) dot = fmaf(efs[w][i], W1[i * HD + lane], dot);
  float hv = dot + b1[lane];
  hv = 0.5f * hv * (1.f + erff(hv * 0.70710678118654752f));
  float p = hv * W2[lane];
#pragma unroll
  for (int off = 32; off; off >>= 1) p += __shfl_xor(p, off, 64);
  if (lane == 0) scores[(size_t)(b * NH + h) * E + e] = (p + b2[0]) * 0.125f;
}

// ---------------- softmax over E per (b,h), then *= edge_weight[h] ----------------
__global__ __launch_bounds__(256) void softmax_ew(float* __restrict__ scores,
                                                  const float* __restrict__ ew, int E) {
  const int row = blockIdx.x;
  const int h = row & (NH - 1);
  float* s = scores + (size_t)row * E;
  const int tid = threadIdx.x, lane = tid & 63, w = tid >> 6;
  __shared__ float red[4];

  float vals[8];
  float mx = -1e30f;
#pragma unroll
  for (int i = 0; i < 8; i++) {
    int j = tid + i * 256;
    vals[i] = (j < E) ? s[j] : -1e30f;
    mx = fmaxf(mx, vals[i]);
  }
#pragma unroll
  for (int off = 32; off; off >>= 1) mx = fmaxf(mx, __shfl_xor(mx, off, 64));
  if (lane == 0) red[w] = mx;
  __syncthreads();
  mx = fmaxf(fmaxf(red[0], red[1]), fmaxf(red[2], red[3]));
  __syncthreads();

  float sum = 0.f;
#pragma unroll
  for (int i = 0; i < 8; i++) {
    vals[i] = __expf(vals[i] - mx);
    if (tid + i * 256 < E) sum += vals[i];
  }
#pragma unroll
  for (int off = 32; off; off >>= 1) sum += __shfl_xor(sum, off, 64);
  if (lane == 0) red[w] = sum;
  __syncthreads();
  sum = red[0] + red[1] + red[2] + red[3];

  const float scaleout = ew[h] / sum;
#pragma unroll
  for (int i = 0; i < 8; i++) {
    int j = tid + i * 256;
    if (j < E) s[j] = vals[i] * scaleout;
  }
}

// ---------------- wrow[b*E+e][d] = attn[b,h(d),e] * vd[b*E+e][d] ----------------
__global__ __launch_bounds__(256) void weight_rows(const float* __restrict__ vd,
                                                   const float* __restrict__ attn,
                                                   float* __restrict__ wrow, int E) {
  const int row = blockIdx.x;  // b*E + e
  const int b = row / E, e = row - b * E;
  const int d = threadIdx.x * 4;
  const int h = d >> 6;
  const float a = attn[(size_t)(b * NH + h) * E + e];
  float4 v = *(const float4*)(vd + (size_t)row * DIMK + d);
  v.x *= a; v.y *= a; v.z *= a; v.w *= a;
  *(float4*)(wrow + (size_t)row * DIMK + d) = v;
}

// ---------------- fold duplicate-src edges into primary edge rows ----------------
__global__ __launch_bounds__(256) void dup_add(const int* __restrict__ f,
                                               float* __restrict__ wrow, int E) {
  const int e = blockIdx.x;
  const int fe = f[e];
  if (fe == e) return;
  const int d = threadIdx.x * 4;
#pragma unroll
  for (int b = 0; b < BB; b++) {
    const float4 v = *(const float4*)(wrow + (size_t)(b * E + e) * DIMK + d);
    float* dst = wrow + (size_t)(b * E + fe) * DIMK + d;
    atomicAdd(dst + 0, v.x);
    atomicAdd(dst + 1, v.y);
    atomicAdd(dst + 2, v.z);
    atomicAdd(dst + 3, v.w);
  }
}

extern "C" void kernel_launch(void* const* d_in, const int* in_sizes, int n_in,
                              void* d_out, int out_size, void* d_ws, size_t ws_size,
                              hipStream_t stream) {
  const float* x = (const float*)d_in[0];
  const int* src = (const int*)d_in[1];
  const int* dst = (const int*)d_in[2];
  const float* Wq = (const float*)d_in[3];
  const float* bq = (const float*)d_in[4];
  const float* Wk = (const float*)d_in[5];
  const float* bk = (const float*)d_in[6];
  const float* Wv = (const float*)d_in[7];
  const float* bv = (const float*)d_in[8];
  const float* Wo = (const float*)d_in[9];
  const float* bo = (const float*)d_in[10];
  const float* ew = (const float*)d_in[11];
  const float* W1 = (const float*)d_in[12];
  const float* b1 = (const float*)d_in[13];
  const float* W2 = (const float*)d_in[14];
  const float* b2 = (const float*)d_in[15];
  float* out = (float*)d_out;

  const int E = in_sizes[1];
  const int M = BB * E;

  char* w = (char*)d_ws;
  float* qs = (float*)w; w += (size_t)M * DIMK * 4;   // also vd
  float* kd = (float*)w; w += (size_t)M * DIMK * 4;   // also wrow
  float* sc = (float*)w; w += (size_t)BB * NH * E * 4;
  int* fidx = (int*)w; w += (((size_t)E * 4) + 255) & ~(size_t)255;
  const size_t WSZ = (size_t)DIMK * DIMK;
  unsigned short* WqT_hi = (unsigned short*)w;
  unsigned short* WqT_lo = WqT_hi + WSZ;
  unsigned short* WkT_hi = WqT_lo + WSZ;
  unsigned short* WkT_lo = WkT_hi + WSZ;
  unsigned short* WvT_hi = WkT_lo + WSZ;
  unsigned short* WvT_lo = WvT_hi + WSZ;
  unsigned short* WoT_hi = WvT_lo + WSZ;
  unsigned short* WoT_lo = WoT_hi + WSZ;

  float* vd = qs;
  float* wrow = kd;

  // 1) fill output with bo (rows not touched by src keep exactly bo)
  const int total4 = BB * SS * (DIMK / 4);
  fill_out_kernel<<<2048, 256, 0, stream>>>((const float4*)bo, (float4*)out, total4);

  // 2) weight prep (split + transpose)
  dim3 gw(16, 16);
  prep_w<<<gw, 256, 0, stream>>>(Wq, WqT_hi, WqT_lo);
  prep_w<<<gw, 256, 0, stream>>>(Wk, WkT_hi, WkT_lo);
  prep_w<<<gw, 256, 0, stream>>>(Wv, WvT_hi, WvT_lo);
  prep_w<<<gw, 256, 0, stream>>>(Wo, WoT_hi, WoT_lo);

  // 3) first-occurrence map
  calc_first<<<(E + 255) / 256, 256, 0, stream>>>(src, fidx, E);

  dim3 g1((M + 127) / 128, DIMK / 128);
  // 4) q/k projections (gathered rows)
  gemm_split<0><<<g1, 256, 0, stream>>>(x, src, WqT_hi, WqT_lo, bq, qs, nullptr, nullptr, M, E);
  gemm_split<0><<<g1, 256, 0, stream>>>(x, dst, WkT_hi, WkT_lo, bk, kd, nullptr, nullptr, M, E);

  // 5) edge MLP -> scores
  edge_scores<<<(BB * NH * E) / 4, 256, 0, stream>>>(qs, kd, W1, b1, W2, b2, sc, E);

  // 6) softmax over edges + edge_weight
  softmax_ew<<<BB * NH, 256, 0, stream>>>(sc, ew, E);

  // 7) v projection (reuses qs buffer)
  gemm_split<0><<<g1, 256, 0, stream>>>(x, dst, WvT_hi, WvT_lo, bv, vd, nullptr, nullptr, M, E);

  // 8) weighted rows, fold duplicates
  weight_rows<<<M, 256, 0, stream>>>(vd, sc, wrow, E);
  dup_add<<<E, 256, 0, stream>>>(fidx, wrow, E);

  // 9) final GEMM: wrow @ Wo, plain guarded scatter-store (no atomics)
  gemm_split<1><<<g1, 256, 0, stream>>>(wrow, nullptr, WoT_hi, WoT_lo, bo, out, fidx, src, M, E);
}

// Round 3
// 489.367 us; speedup vs baseline: 2.5631x; 1.3176x over previous
//
#include <hip/hip_runtime.h>
#include <hip/hip_bf16.h>
#include <math.h>

#define DIMK 1024
#define NH 16
#define HD 64
#define BB 4
#define SS 8192

typedef __attribute__((ext_vector_type(8))) short bf16x8;
typedef __attribute__((ext_vector_type(8))) unsigned short ushort8;
typedef __attribute__((ext_vector_type(4))) float f32x4;

#define MFMA16(a, b, c) __builtin_amdgcn_mfma_f32_16x16x32_bf16((a), (b), (c), 0, 0, 0)

__device__ __forceinline__ unsigned short f32_to_bf16_rne(float f) {
  unsigned int u = __float_as_uint(f);
  u = (u + 0x7fffu + ((u >> 16) & 1u)) >> 16;
  return (unsigned short)u;
}
__device__ __forceinline__ float bf16_bits_to_f32(unsigned short b) {
  return __uint_as_float(((unsigned int)b) << 16);
}

// ---------------- fill d_out with bo broadcast ----------------
__global__ __launch_bounds__(256) void fill_out_kernel(const float4* __restrict__ bo4,
                                                       float4* __restrict__ out, int total4) {
  for (int i = blockIdx.x * 256 + threadIdx.x; i < total4; i += gridDim.x * 256)
    out[i] = bo4[i & 255];  // DIMK/4 == 256
}

// ---------------- split W [k][n] fp32 -> WT_hi/WT_lo [n][k] bf16 ----------------
__global__ __launch_bounds__(256) void prep_w(const float* __restrict__ W,
                                              unsigned short* __restrict__ WT_hi,
                                              unsigned short* __restrict__ WT_lo) {
  __shared__ float st[64][65];
  const int bk = blockIdx.x * 64, bn = blockIdx.y * 64;
  const int t = threadIdx.x;
  const int lr = t >> 4, lc = (t & 15) * 4;
#pragma unroll
  for (int i = 0; i < 4; i++) {
    int k = lr + i * 16;
    float4 v = *(const float4*)(W + (size_t)(bk + k) * DIMK + bn + lc);
    st[k][lc] = v.x; st[k][lc + 1] = v.y; st[k][lc + 2] = v.z; st[k][lc + 3] = v.w;
  }
  __syncthreads();
#pragma unroll
  for (int i = 0; i < 4; i++) {
    int n = lr + i * 16;
    unsigned long long ph = 0, pl = 0;
#pragma unroll
    for (int j = 0; j < 4; j++) {
      float v = st[lc + j][n];
      unsigned short hb = f32_to_bf16_rne(v);
      unsigned short lb = f32_to_bf16_rne(v - bf16_bits_to_f32(hb));
      ph |= ((unsigned long long)hb) << (16 * j);
      pl |= ((unsigned long long)lb) << (16 * j);
    }
    *(unsigned long long*)(WT_hi + (size_t)(bn + n) * DIMK + bk + lc) = ph;
    *(unsigned long long*)(WT_lo + (size_t)(bn + n) * DIMK + bk + lc) = pl;
  }
}

// ---------------- first-occurrence map via atomicMin table ----------------
__global__ __launch_bounds__(256) void init_table(int* __restrict__ t) {
  t[blockIdx.x * 256 + threadIdx.x] = 0x7fffffff;
}
__global__ __launch_bounds__(256) void build_first(const int* __restrict__ src,
                                                   int* __restrict__ t, int E) {
  int e = blockIdx.x * 256 + threadIdx.x;
  if (e < E) atomicMin(&t[src[e]], e);
}
__global__ __launch_bounds__(256) void read_first(const int* __restrict__ src,
                                                  const int* __restrict__ t,
                                                  int* __restrict__ f, int E) {
  int e = blockIdx.x * 256 + threadIdx.x;
  if (e < E) f[e] = t[src[e]];
}

// ---------------- split-bf16 MFMA GEMM ----------------
// MODE 0: A row m -> X[b*SS + gidx[e]] (gather), store out[m*ldc + n] = acc + bias_sel(n)
// MODE 1: A row m -> X[m], store out[(b*SS+srci[e])*ldc + n] = acc + bias[n] iff fidx[e]==e
template <int MODE>
__global__ __launch_bounds__(256) void gemm_split(
    const float* __restrict__ X, const int* __restrict__ gidx,
    const unsigned short* __restrict__ BT_hi, const unsigned short* __restrict__ BT_lo,
    const float* __restrict__ bias, const float* __restrict__ bias2,
    float* __restrict__ out, int ldc,
    const int* __restrict__ fidx, const int* __restrict__ srci, int M, int E) {
  __shared__ unsigned short As_hi[128][40];
  __shared__ unsigned short As_lo[128][40];
  __shared__ unsigned short Bs_hi[128][40];
  __shared__ unsigned short Bs_lo[128][40];

  const int tid = threadIdx.x;
  const int m0 = blockIdx.x * 128, n0 = blockIdx.y * 128;
  const int lane = tid & 63, w = tid >> 6;
  const int wm0 = (w >> 1) * 64, wn0 = (w & 1) * 64;

  const int sm = tid >> 1;
  const int skq = (tid & 1) * 16;

  const int mg = m0 + sm;
  const float* arow;
  if (MODE == 0) {
    int mgc = (mg < M) ? mg : 0;
    int b = mgc / E, e = mgc - b * E;
    arow = X + ((size_t)b * SS + gidx[e]) * DIMK;
  } else {
    arow = X + (size_t)((mg < M) ? mg : 0) * DIMK;
  }
  const unsigned short* bhrow = BT_hi + (size_t)(n0 + sm) * DIMK;
  const unsigned short* blrow = BT_lo + (size_t)(n0 + sm) * DIMK;

  f32x4 acc[4][4];
#pragma unroll
  for (int i = 0; i < 4; i++)
#pragma unroll
    for (int j = 0; j < 4; j++) acc[i][j] = (f32x4){0.f, 0.f, 0.f, 0.f};

  for (int k0 = 0; k0 < DIMK; k0 += 32) {
    float4 a0 = *(const float4*)(arow + k0 + skq);
    float4 a1 = *(const float4*)(arow + k0 + skq + 4);
    float4 a2 = *(const float4*)(arow + k0 + skq + 8);
    float4 a3 = *(const float4*)(arow + k0 + skq + 12);
    ushort8 gbh0 = *(const ushort8*)(bhrow + k0 + skq);
    ushort8 gbh1 = *(const ushort8*)(bhrow + k0 + skq + 8);
    ushort8 gbl0 = *(const ushort8*)(blrow + k0 + skq);
    ushort8 gbl1 = *(const ushort8*)(blrow + k0 + skq + 8);

    float av[16];
    *(float4*)&av[0] = a0; *(float4*)&av[4] = a1;
    *(float4*)&av[8] = a2; *(float4*)&av[12] = a3;
    ushort8 h0, h1, l0, l1;
#pragma unroll
    for (int i = 0; i < 8; i++) {
      unsigned short hb = f32_to_bf16_rne(av[i]);
      h0[i] = hb;
      l0[i] = f32_to_bf16_rne(av[i] - bf16_bits_to_f32(hb));
    }
#pragma unroll
    for (int i = 0; i < 8; i++) {
      unsigned short hb = f32_to_bf16_rne(av[8 + i]);
      h1[i] = hb;
      l1[i] = f32_to_bf16_rne(av[8 + i] - bf16_bits_to_f32(hb));
    }

    __syncthreads();
    *(ushort8*)&As_hi[sm][skq] = h0;
    *(ushort8*)&As_hi[sm][skq + 8] = h1;
    *(ushort8*)&As_lo[sm][skq] = l0;
    *(ushort8*)&As_lo[sm][skq + 8] = l1;
    *(ushort8*)&Bs_hi[sm][skq] = gbh0;
    *(ushort8*)&Bs_hi[sm][skq + 8] = gbh1;
    *(ushort8*)&Bs_lo[sm][skq] = gbl0;
    *(ushort8*)&Bs_lo[sm][skq + 8] = gbl1;
    __syncthreads();

    bf16x8 fah[4], fal[4], fbh[4], fbl[4];
    const int kk = (lane >> 4) * 8;
    const int rr = lane & 15;
#pragma unroll
    for (int f = 0; f < 4; f++) {
      fah[f] = *(bf16x8*)&As_hi[wm0 + f * 16 + rr][kk];
      fal[f] = *(bf16x8*)&As_lo[wm0 + f * 16 + rr][kk];
      fbh[f] = *(bf16x8*)&Bs_hi[wn0 + f * 16 + rr][kk];
      fbl[f] = *(bf16x8*)&Bs_lo[wn0 + f * 16 + rr][kk];
    }
#pragma unroll
    for (int mf = 0; mf < 4; mf++)
#pragma unroll
      for (int nf = 0; nf < 4; nf++) {
        acc[mf][nf] = MFMA16(fah[mf], fbh[nf], acc[mf][nf]);
        acc[mf][nf] = MFMA16(fah[mf], fbl[nf], acc[mf][nf]);
        acc[mf][nf] = MFMA16(fal[mf], fbh[nf], acc[mf][nf]);
      }
  }

  const int cq = lane >> 4, cr = lane & 15;
#pragma unroll
  for (int nf = 0; nf < 4; nf++) {
    const int col = n0 + wn0 + nf * 16 + cr;
    const float bv = (MODE == 0 && bias2 != nullptr && col >= DIMK) ? bias2[col - DIMK]
                                                                    : bias[col & (DIMK - 1)];
#pragma unroll
    for (int mf = 0; mf < 4; mf++) {
#pragma unroll
      for (int r = 0; r < 4; r++) {
        const int mrow = m0 + wm0 + mf * 16 + cq * 4 + r;
        if (mrow >= M) continue;
        if (MODE == 0) {
          out[(size_t)mrow * ldc + col] = acc[mf][nf][r] + bv;
        } else {
          int b = mrow / E, e = mrow - b * E;
          if (fidx[e] == e) {
            int orow = b * SS + srci[e];
            out[(size_t)orow * ldc + col] = acc[mf][nf][r] + bv;
          }
        }
      }
    }
  }
}

// ---------------- edge MLP scores: one wave per (b,h,e) ----------------
__global__ __launch_bounds__(256) void edge_scores(
    const float* __restrict__ qs, const float* __restrict__ kd, int ldk,
    const float* __restrict__ W1, const float* __restrict__ b1,
    const float* __restrict__ W2, const float* __restrict__ b2,
    float* __restrict__ scores, int E) {
  __shared__ float efs[4][128];
  const int w = threadIdx.x >> 6, lane = threadIdx.x & 63;
  const int eh = blockIdx.x * 4 + w;
  const int HE = NH * E;
  const int b = eh / HE;
  const int r = eh - b * HE;
  const int h = r / E;
  const int e = r - h * E;
  efs[w][lane] = qs[((size_t)(b * E + e)) * DIMK + h * HD + lane];
  efs[w][64 + lane] = kd[((size_t)(b * E + e)) * ldk + h * HD + lane];
  __syncthreads();
  float dot = 0.f;
#pragma unroll 16
  for (int i = 0; i < 128; i++) dot = fmaf(efs[w][i], W1[i * HD + lane], dot);
  float hv = dot + b1[lane];
  hv = 0.5f * hv * (1.f + erff(hv * 0.70710678118654752f));
  float p = hv * W2[lane];
#pragma unroll
  for (int off = 32; off; off >>= 1) p += __shfl_xor(p, off, 64);
  if (lane == 0) scores[(size_t)(b * NH + h) * E + e] = (p + b2[0]) * 0.125f;
}

// ---------------- softmax over E per (b,h), then *= edge_weight[h] ----------------
__global__ __launch_bounds__(256) void softmax_ew(float* __restrict__ scores,
                                                  const float* __restrict__ ew, int E) {
  const int row = blockIdx.x;
  const int h = row & (NH - 1);
  float* s = scores + (size_t)row * E;
  const int tid = threadIdx.x, lane = tid & 63, w = tid >> 6;
  __shared__ float red[4];

  float vals[8];
  float mx = -1e30f;
#pragma unroll
  for (int i = 0; i < 8; i++) {
    int j = tid + i * 256;
    vals[i] = (j < E) ? s[j] : -1e30f;
    mx = fmaxf(mx, vals[i]);
  }
#pragma unroll
  for (int off = 32; off; off >>= 1) mx = fmaxf(mx, __shfl_xor(mx, off, 64));
  if (lane == 0) red[w] = mx;
  __syncthreads();
  mx = fmaxf(fmaxf(red[0], red[1]), fmaxf(red[2], red[3]));
  __syncthreads();

  float sum = 0.f;
#pragma unroll
  for (int i = 0; i < 8; i++) {
    vals[i] = __expf(vals[i] - mx);
    if (tid + i * 256 < E) sum += vals[i];
  }
#pragma unroll
  for (int off = 32; off; off >>= 1) sum += __shfl_xor(sum, off, 64);
  if (lane == 0) red[w] = sum;
  __syncthreads();
  sum = red[0] + red[1] + red[2] + red[3];

  const float scaleout = ew[h] / sum;
#pragma unroll
  for (int i = 0; i < 8; i++) {
    int j = tid + i * 256;
    if (j < E) s[j] = vals[i] * scaleout;
  }
}

// ---------------- wrow[b*E+e][d] = attn[b,h(d),e] * vd[(b*E+e)*ldv + d] ----------------
__global__ __launch_bounds__(256) void weight_rows(const float* __restrict__ vd, int ldv,
                                                   const float* __restrict__ attn,
                                                   float* __restrict__ wrow, int E) {
  const int row = blockIdx.x;  // b*E + e
  const int b = row / E, e = row - b * E;
  const int d = threadIdx.x * 4;
  const int h = d >> 6;
  const float a = attn[(size_t)(b * NH + h) * E + e];
  float4 v = *(const float4*)(vd + (size_t)row * ldv + d);
  v.x *= a; v.y *= a; v.z *= a; v.w *= a;
  *(float4*)(wrow + (size_t)row * DIMK + d) = v;
}

// ---------------- fold duplicate-src edges into primary edge rows ----------------
__global__ __launch_bounds__(256) void dup_add(const int* __restrict__ f,
                                               float* __restrict__ wrow, int E) {
  const int e = blockIdx.x;
  const int fe = f[e];
  if (fe == e) return;
  const int d = threadIdx.x * 4;
#pragma unroll
  for (int b = 0; b < BB; b++) {
    const float4 v = *(const float4*)(wrow + (size_t)(b * E + e) * DIMK + d);
    float* dst = wrow + (size_t)(b * E + fe) * DIMK + d;
    atomicAdd(dst + 0, v.x);
    atomicAdd(dst + 1, v.y);
    atomicAdd(dst + 2, v.z);
    atomicAdd(dst + 3, v.w);
  }
}

extern "C" void kernel_launch(void* const* d_in, const int* in_sizes, int n_in,
                              void* d_out, int out_size, void* d_ws, size_t ws_size,
                              hipStream_t stream) {
  const float* x = (const float*)d_in[0];
  const int* src = (const int*)d_in[1];
  const int* dst = (const int*)d_in[2];
  const float* Wq = (const float*)d_in[3];
  const float* bq = (const float*)d_in[4];
  const float* Wk = (const float*)d_in[5];
  const float* bk = (const float*)d_in[6];
  const float* Wv = (const float*)d_in[7];
  const float* bv = (const float*)d_in[8];
  const float* Wo = (const float*)d_in[9];
  const float* bo = (const float*)d_in[10];
  const float* ew = (const float*)d_in[11];
  const float* W1 = (const float*)d_in[12];
  const float* b1 = (const float*)d_in[13];
  const float* W2 = (const float*)d_in[14];
  const float* b2 = (const float*)d_in[15];
  float* out = (float*)d_out;

  const int E = in_sizes[1];
  const int M = BB * E;

  char* w = (char*)d_ws;
  float* qs = (float*)w; w += (size_t)M * DIMK * 4;        // 32.8 MB (aliased by wrow later)
  float* kv = (float*)w; w += (size_t)M * 2048 * 4;        // 65.5 MB
  float* sc = (float*)w; w += (size_t)BB * NH * E * 4;
  int* table = (int*)w; w += (size_t)SS * 4;
  int* fidx = (int*)w; w += (((size_t)E * 4) + 255) & ~(size_t)255;
  const size_t WSZ = (size_t)DIMK * DIMK;
  unsigned short* WqT_hi = (unsigned short*)w;
  unsigned short* WqT_lo = WqT_hi + WSZ;
  unsigned short* WkvT_hi = WqT_lo + WSZ;       // 2048 rows
  unsigned short* WkvT_lo = WkvT_hi + 2 * WSZ;
  unsigned short* WoT_hi = WkvT_lo + 2 * WSZ;
  unsigned short* WoT_lo = WoT_hi + WSZ;

  float* wrow = qs;  // qs is dead after edge_scores

  // 1) fill output with bo
  const int total4 = BB * SS * (DIMK / 4);
  fill_out_kernel<<<2048, 256, 0, stream>>>((const float4*)bo, (float4*)out, total4);

  // 2) weight prep (split + transpose); Wk and Wv concatenated along N
  dim3 gw(16, 16);
  prep_w<<<gw, 256, 0, stream>>>(Wq, WqT_hi, WqT_lo);
  prep_w<<<gw, 256, 0, stream>>>(Wk, WkvT_hi, WkvT_lo);
  prep_w<<<gw, 256, 0, stream>>>(Wv, WkvT_hi + (size_t)1024 * DIMK, WkvT_lo + (size_t)1024 * DIMK);
  prep_w<<<gw, 256, 0, stream>>>(Wo, WoT_hi, WoT_lo);

  // 3) first-occurrence map (atomicMin table)
  init_table<<<SS / 256, 256, 0, stream>>>(table);
  build_first<<<(E + 255) / 256, 256, 0, stream>>>(src, table, E);
  read_first<<<(E + 255) / 256, 256, 0, stream>>>(src, table, fidx, E);

  const int gx = (M + 127) / 128;
  // 4) q projection (src gather)
  gemm_split<0><<<dim3(gx, 8), 256, 0, stream>>>(x, src, WqT_hi, WqT_lo, bq, nullptr, qs,
                                                 DIMK, nullptr, nullptr, M, E);
  // 5) fused k|v projection (dst gather, N=2048)
  gemm_split<0><<<dim3(gx, 16), 256, 0, stream>>>(x, dst, WkvT_hi, WkvT_lo, bk, bv, kv,
                                                  2048, nullptr, nullptr, M, E);

  // 6) edge MLP -> scores (k at kv offset 0, stride 2048)
  edge_scores<<<(BB * NH * E) / 4, 256, 0, stream>>>(qs, kv, 2048, W1, b1, W2, b2, sc, E);

  // 7) softmax over edges + edge_weight
  softmax_ew<<<BB * NH, 256, 0, stream>>>(sc, ew, E);

  // 8) weighted rows (v at kv offset 1024), fold duplicates
  weight_rows<<<M, 256, 0, stream>>>(kv + 1024, 2048, sc, wrow, E);
  dup_add<<<E, 256, 0, stream>>>(fidx, wrow, E);

  // 9) final GEMM: wrow @ Wo, guarded scatter-store (no atomics)
  gemm_split<1><<<dim3(gx, 8), 256, 0, stream>>>(wrow, nullptr, WoT_hi, WoT_lo, bo, nullptr,
                                                 out, DIMK, fidx, src, M, E);
}